// Round 14
// baseline (155.597 us; speedup 1.0000x reference)
//
#include <hip/hip_runtime.h>
#include <stdint.h>

typedef unsigned short u16;
typedef __attribute__((ext_vector_type(8))) short short8;
typedef __attribute__((ext_vector_type(4))) float f32x4;

#define B_      16
#define L_      1024
#define H_      1024
#define G_      128
#define M_TOT   16368            // B*(L-1)
#define K_TOT   3072
#define OUT_SEG 2095104          // M_TOT*G_
#define KL_IDX  (4*OUT_SEG)
#define KL_BLOCKS 4092           // M_TOT / 4 exactly

// ws layout
#define WS_WT_OFF    0           // bf16 W'T [512][3072] = 3,145,728 B
#define WS_BIAS_OFF  3145728     // float[512]
#define WS_PART_OFF  3147776     // float[4092] block partials

__device__ inline u16 f2bf(float f) {
    union { float f; uint32_t u; } x; x.f = f;
    uint32_t u = x.u;
    return (u16)((u + 0x7fffu + ((u >> 16) & 1u)) >> 16);
}

__device__ inline void gload16(const void* g, void* l) {
    __builtin_amdgcn_global_load_lds(
        (const __attribute__((address_space(1))) void*)g,
        (__attribute__((address_space(3))) void*)l, 16, 0, 0);
}

__device__ inline short8 cvt8(f32x4 x, f32x4 y) {
    union { short8 s; uint32_t u[4]; } r;
    asm("v_cvt_pk_bf16_f32 %0, %1, %2" : "=v"(r.u[0]) : "v"(x[0]), "v"(x[1]));
    asm("v_cvt_pk_bf16_f32 %0, %1, %2" : "=v"(r.u[1]) : "v"(x[2]), "v"(x[3]));
    asm("v_cvt_pk_bf16_f32 %0, %1, %2" : "=v"(r.u[2]) : "v"(y[0]), "v"(y[1]));
    asm("v_cvt_pk_bf16_f32 %0, %1, %2" : "=v"(r.u[3]) : "v"(y[2]), "v"(y[3]));
    return r.s;
}

// ---------------- prep: build W'T (bf16, [512][3072]) + bias[512] ------------
__global__ __launch_bounds__(256) void prep_kernel(
    const float* __restrict__ Wzm, const float* __restrict__ bzm,
    const float* __restrict__ Wzv, const float* __restrict__ bzv,
    const float* __restrict__ Wqm, const float* __restrict__ bqm,
    const float* __restrict__ Wqv, const float* __restrict__ bqv,
    u16* __restrict__ wt, float* __restrict__ bias)
{
    int n = blockIdx.x;                 // 0..511 (output column)
    int tid = threadIdx.x;
    const float* W; const float* bsrc; int g; int kmax;
    if (n < 128)      { W = Wzm; bsrc = bzm; g = n;       kmax = 2048; }
    else if (n < 256) { W = Wzv; bsrc = bzv; g = n - 128; kmax = 2048; }
    else if (n < 384) { W = Wqm; bsrc = bqm; g = n - 256; kmax = 3072; }
    else              { W = Wqv; bsrc = bqv; g = n - 384; kmax = 3072; }
    if (tid == 0) bias[n] = bsrc[g];
    #pragma unroll
    for (int i = 0; i < 12; ++i) {
        int k = i * 256 + tid;
        float v = (k < kmax) ? W[(size_t)k * G_ + g] : 0.0f;
        wt[(size_t)n * K_TOT + k] = f2bf(v);
    }
}

// ---------------- GEMM: out[m, 0:512] = ce @ W' + bias ----------------------
// BM=128, BN=128, BK=32, 4 waves (2x2 of 64x64), 512 blocks (2/CU).
// A: fp32 via global_load_lds into a 3-deep LDS ring (source-preswizzled,
//    chunk ^= r&7) -- R9-verified path, byte-identical.
// B: NEVER in LDS. Per-wave VGPR fragments loaded directly from wt (L2-hot),
//    double-buffered one phase ahead (named X/Y sets, no arrays).
// Counted vmcnt: per phase issue B(t+1) then A(t+2); queue =
// {A(t),B(t),A(t+1),B(t+1),A(t+2)} = 20 -> WAITV(12) drains A(t)+B(t).
__global__ __launch_bounds__(256, 2) void gemm_kernel(
    const float* __restrict__ events, const float* __restrict__ contexts,
    const u16* __restrict__ wt, const float* __restrict__ bias,
    float* __restrict__ out)
{
    __shared__ float Af[3][128 * 32];   // fp32 A tiles, swizzled (16 KB each)

    const int tid  = threadIdx.x;
    const int bid  = blockIdx.x;
    // XCD swizzle: the 4 nb-blocks sharing an A panel land on one XCD.
    const int xcd  = bid & 7;
    const int nb   = (bid >> 3) & 3;
    const int mp   = xcd * 16 + (bid >> 5);
    const int m0   = mp * 128;

    const int lane = tid & 63;
    const int w    = tid >> 6;
    const int wm   = (w >> 1) * 64;
    const int wn   = (w & 1) * 64;
    const int lr   = lane & 15;
    const int kg   = lane >> 4;          // 0..3

    // ---- A staging sources: 4 chunks/thread, chunk c = it*256+tid ->
    //      row r=c>>3, dest chunk cd=c&7, source chunk cs=cd^(r&7).
    const float* aS0[4]; const float* aS1[4]; const float* aS2[4];
    #pragma unroll
    for (int it = 0; it < 4; ++it) {
        int c  = it * 256 + tid;
        int r  = c >> 3;
        int cs = (c & 7) ^ (r & 7);
        int m = m0 + r; if (m > M_TOT - 1) m = M_TOT - 1;
        int b = m / 1023;
        int t = m - b * 1023;
        aS0[it] = events   + ((size_t)(b * L_ + t)) * H_ + cs * 4;
        aS1[it] = aS0[it] + H_;
        aS2[it] = contexts + ((size_t)(b * (L_ - 1) + t)) * H_ + cs * 4;
    }

    // ---- B fragment base pointers (direct global, per-wave) ----
    const u16* bp0 = wt + (size_t)(nb * 128 + wn +  0 + lr) * K_TOT + kg * 8;
    const u16* bp1 = wt + (size_t)(nb * 128 + wn + 16 + lr) * K_TOT + kg * 8;
    const u16* bp2 = wt + (size_t)(nb * 128 + wn + 32 + lr) * K_TOT + kg * 8;
    const u16* bp3 = wt + (size_t)(nb * 128 + wn + 48 + lr) * K_TOT + kg * 8;

    // ---- A fragment read offsets (fp32, swizzled) ----
    int aoff[4][2];
    #pragma unroll
    for (int i = 0; i < 4; ++i) {
        int row = wm + i * 16 + lr;
        aoff[i][0] = row * 32 + (((2 * kg)     ^ (row & 7)) << 2);
        aoff[i][1] = row * 32 + (((2 * kg + 1) ^ (row & 7)) << 2);
    }

    f32x4 acc[4][4];
    #pragma unroll
    for (int i = 0; i < 4; ++i)
        #pragma unroll
        for (int j = 0; j < 4; ++j)
            acc[i][j] = (f32x4){0.f, 0.f, 0.f, 0.f};

    // Named B fragment sets (double-buffered, no arrays -> no scratch)
    short8 BX0, BX1, BX2, BX3;
    short8 BY0, BY1, BY2, BY3;

#define BLOAD(p, KT)                                                           \
    {                                                                          \
        p##0 = *(const short8*)(bp0 + (KT) * 32);                              \
        p##1 = *(const short8*)(bp1 + (KT) * 32);                              \
        p##2 = *(const short8*)(bp2 + (KT) * 32);                              \
        p##3 = *(const short8*)(bp3 + (KT) * 32);                              \
    }

#define STAGEA(SLOT, KT)                                                       \
    {                                                                          \
        int k0_ = (KT) * 32;                                                   \
        int rg_ = k0_ >> 10;                                                   \
        int kq_ = k0_ & 1023;                                                  \
        _Pragma("unroll")                                                      \
        for (int it = 0; it < 4; ++it) {                                       \
            const float* s_ = (rg_ == 0) ? aS0[it]                             \
                             : (rg_ == 1 ? aS1[it] : aS2[it]);                 \
            gload16(s_ + kq_, &Af[SLOT][(it * 256 + tid) * 4]);                \
        }                                                                      \
    }

#define COMPUTE(BUF, p)                                                        \
    {                                                                          \
        short8 a_[4];                                                          \
        _Pragma("unroll")                                                      \
        for (int i = 0; i < 4; ++i) {                                          \
            f32x4 x_ = *(const f32x4*)&Af[BUF][aoff[i][0]];                    \
            f32x4 y_ = *(const f32x4*)&Af[BUF][aoff[i][1]];                    \
            a_[i] = cvt8(x_, y_);                                              \
        }                                                                      \
        _Pragma("unroll")                                                      \
        for (int i = 0; i < 4; ++i) {                                          \
            acc[i][0] = __builtin_amdgcn_mfma_f32_16x16x32_bf16(a_[i], p##0, acc[i][0], 0, 0, 0); \
            acc[i][1] = __builtin_amdgcn_mfma_f32_16x16x32_bf16(a_[i], p##1, acc[i][1], 0, 0, 0); \
            acc[i][2] = __builtin_amdgcn_mfma_f32_16x16x32_bf16(a_[i], p##2, acc[i][2], 0, 0, 0); \
            acc[i][3] = __builtin_amdgcn_mfma_f32_16x16x32_bf16(a_[i], p##3, acc[i][3], 0, 0, 0); \
        }                                                                      \
    }

#define WAITV(N)                                                               \
    asm volatile("s_waitcnt vmcnt(" #N ")" ::: "memory");                      \
    __builtin_amdgcn_sched_barrier(0);
#define LGKM0                                                                  \
    asm volatile("s_waitcnt lgkmcnt(0)" ::: "memory");                         \
    __builtin_amdgcn_sched_barrier(0);
#define BAR __builtin_amdgcn_s_barrier()

#define PHASE(BUF, TGT, PC, PN, KT)                                            \
    BLOAD(PN, (KT) + 1);                                                       \
    STAGEA(TGT, (KT) + 2);                                                     \
    WAITV(12); BAR;                                                            \
    COMPUTE(BUF, PC);                                                          \
    LGKM0; BAR;

    // prologue: A(0), B(0), A(1) in flight (queue = 12)
    STAGEA(0, 0);
    BLOAD(BX, 0);
    STAGEA(1, 1);

    // phases 0..89 (6-phase super-iterations: slots 0,1,2 x B-parity X,Y)
    for (int t = 0; t < 90; t += 6) {
        PHASE(0, 2, BX, BY, t);
        PHASE(1, 0, BY, BX, t + 1);
        PHASE(2, 1, BX, BY, t + 2);
        PHASE(0, 2, BY, BX, t + 3);
        PHASE(1, 0, BX, BY, t + 4);
        PHASE(2, 1, BY, BX, t + 5);
    }
    // phases 90..93
    PHASE(0, 2, BX, BY, 90);
    PHASE(1, 0, BY, BX, 91);
    PHASE(2, 1, BX, BY, 92);
    PHASE(0, 2, BY, BX, 93);
    // phase 94: issue B(95) only; queue = {A94,B94,A95,B95} = 16 -> drain 8
    BLOAD(BY, 95);
    WAITV(8); BAR;
    COMPUTE(1, BX);
    LGKM0; BAR;
    // phase 95: queue = {A95,B95} = 8 -> drain all
    WAITV(0); BAR;
    COMPUTE(2, BY);

#undef PHASE
#undef BLOAD
#undef STAGEA
#undef COMPUTE
#undef WAITV
#undef LGKM0
#undef BAR

    // epilogue: C row = wm + i*16 + kg*4 + rr ; col = wn + j*16 + lr
    const float* bptr = bias + nb * 128;
    float* obase = out + (size_t)nb * OUT_SEG;
    #pragma unroll
    for (int i = 0; i < 4; ++i) {
        int mloc = wm + i * 16 + kg * 4;
        #pragma unroll
        for (int j = 0; j < 4; ++j) {
            int g = wn + j * 16 + lr;
            float bv = bptr[g];
            #pragma unroll
            for (int rr = 0; rr < 4; ++rr) {
                int mo = m0 + mloc + rr;
                if (mo < M_TOT) obase[(size_t)mo * G_ + g] = acc[i][j][rr] + bv;
            }
        }
    }
}

// ---------------- KL reduction: stage 1 (per-block partials, no atomics) -----
__global__ __launch_bounds__(256) void kl_kernel(const float* __restrict__ out,
                                                 float* __restrict__ partial)
{
    int wid  = threadIdx.x >> 6;
    int row  = blockIdx.x * 4 + wid;        // M_TOT = 4092*4 exactly
    int lane = threadIdx.x & 63;
    const float* zm  = out;
    const float* zlv = out + OUT_SEG;
    const float* qm  = out + (size_t)2 * OUT_SEG;
    const float* qlv = out + (size_t)3 * OUT_SEG;
    size_t base = (size_t)row * G_;
    float s = 0.f;
    #pragma unroll
    for (int hh = 0; hh < 2; ++hh) {
        int g = lane + hh * 64;
        float a = zm[base + g], b = zlv[base + g];
        float c = qm[base + g], d = qlv[base + g];
        float diff = a - c;
        s += d - b + (__expf(b) + diff * diff) * __expf(-d) - 1.0f;
    }
    #pragma unroll
    for (int off = 32; off > 0; off >>= 1)
        s += __shfl_down(s, off);
    __shared__ float pw[4];
    if (lane == 0) pw[wid] = s;
    __syncthreads();
    if (threadIdx.x == 0)
        partial[blockIdx.x] = pw[0] + pw[1] + pw[2] + pw[3];
}

// ---------------- KL reduction: stage 2 --------------------------------------
__global__ __launch_bounds__(256) void kl_final(const float* __restrict__ partial,
                                                float* __restrict__ out)
{
    float s = 0.f;
    for (int i = threadIdx.x; i < KL_BLOCKS; i += 256) s += partial[i];
    #pragma unroll
    for (int off = 32; off > 0; off >>= 1)
        s += __shfl_down(s, off);
    __shared__ float pw[4];
    int wid = threadIdx.x >> 6;
    int lane = threadIdx.x & 63;
    if (lane == 0) pw[wid] = s;
    __syncthreads();
    if (threadIdx.x == 0)
        out[KL_IDX] = 0.5f * (pw[0] + pw[1] + pw[2] + pw[3]) / (float)M_TOT;
}

// ---------------- launcher ----------------------------------------------------
extern "C" void kernel_launch(void* const* d_in, const int* in_sizes, int n_in,
                              void* d_out, int out_size, void* d_ws, size_t ws_size,
                              hipStream_t stream)
{
    const float* events   = (const float*)d_in[0];
    const float* contexts = (const float*)d_in[1];
    const float* Wzm = (const float*)d_in[2];
    const float* bzm = (const float*)d_in[3];
    const float* Wzv = (const float*)d_in[4];
    const float* bzv = (const float*)d_in[5];
    const float* Wqm = (const float*)d_in[6];
    const float* bqm = (const float*)d_in[7];
    const float* Wqv = (const float*)d_in[8];
    const float* bqv = (const float*)d_in[9];
    float* out = (float*)d_out;

    u16*   wt      = (u16*)((char*)d_ws + WS_WT_OFF);
    float* bias    = (float*)((char*)d_ws + WS_BIAS_OFF);
    float* partial = (float*)((char*)d_ws + WS_PART_OFF);

    prep_kernel<<<512, 256, 0, stream>>>(Wzm, bzm, Wzv, bzv, Wqm, bqm, Wqv, bqv,
                                         wt, bias);
    gemm_kernel<<<512, 256, 0, stream>>>(events, contexts, wt, bias, out);
    kl_kernel<<<KL_BLOCKS, 256, 0, stream>>>(out, partial);
    kl_final<<<1, 256, 0, stream>>>(partial, out);
}

// Round 15
// 102.785 us; speedup vs baseline: 1.5138x; 1.5138x over previous
//
#include <hip/hip_runtime.h>
#include <stdint.h>

typedef unsigned short u16;
typedef __attribute__((ext_vector_type(8))) short short8;
typedef __attribute__((ext_vector_type(4))) float f32x4;

#define B_      16
#define L_      1024
#define H_      1024
#define G_      128
#define M_TOT   16368            // B*(L-1)
#define K_TOT   3072
#define OUT_SEG 2095104          // M_TOT*G_
#define KL_IDX  (4*OUT_SEG)
#define KL_BLOCKS 4092           // M_TOT / 4 exactly
#define NKT     48               // K_TOT / 64

// ws layout
#define WS_WT_OFF    0           // bf16 W'T [512][3072] = 3,145,728 B
#define WS_BIAS_OFF  3145728     // float[512]
#define WS_PART_OFF  3147776     // float[4092] block partials

__device__ inline u16 f2bf(float f) {
    union { float f; uint32_t u; } x; x.f = f;
    uint32_t u = x.u;
    return (u16)((u + 0x7fffu + ((u >> 16) & 1u)) >> 16);
}

__device__ inline void gload16(const void* g, void* l) {
    __builtin_amdgcn_global_load_lds(
        (const __attribute__((address_space(1))) void*)g,
        (__attribute__((address_space(3))) void*)l, 16, 0, 0);
}

__device__ inline short8 cvt8(f32x4 x, f32x4 y) {
    union { short8 s; uint32_t u[4]; } r;
    asm("v_cvt_pk_bf16_f32 %0, %1, %2" : "=v"(r.u[0]) : "v"(x[0]), "v"(x[1]));
    asm("v_cvt_pk_bf16_f32 %0, %1, %2" : "=v"(r.u[1]) : "v"(x[2]), "v"(x[3]));
    asm("v_cvt_pk_bf16_f32 %0, %1, %2" : "=v"(r.u[2]) : "v"(y[0]), "v"(y[1]));
    asm("v_cvt_pk_bf16_f32 %0, %1, %2" : "=v"(r.u[3]) : "v"(y[2]), "v"(y[3]));
    return r.s;
}

// ---------------- prep: build W'T (bf16, [512][3072]) + bias[512] ------------
__global__ __launch_bounds__(256) void prep_kernel(
    const float* __restrict__ Wzm, const float* __restrict__ bzm,
    const float* __restrict__ Wzv, const float* __restrict__ bzv,
    const float* __restrict__ Wqm, const float* __restrict__ bqm,
    const float* __restrict__ Wqv, const float* __restrict__ bqv,
    u16* __restrict__ wt, float* __restrict__ bias)
{
    int n = blockIdx.x;                 // 0..511 (output column)
    int tid = threadIdx.x;
    const float* W; const float* bsrc; int g; int kmax;
    if (n < 128)      { W = Wzm; bsrc = bzm; g = n;       kmax = 2048; }
    else if (n < 256) { W = Wzv; bsrc = bzv; g = n - 128; kmax = 2048; }
    else if (n < 384) { W = Wqm; bsrc = bqm; g = n - 256; kmax = 3072; }
    else              { W = Wqv; bsrc = bqv; g = n - 384; kmax = 3072; }
    if (tid == 0) bias[n] = bsrc[g];
    #pragma unroll
    for (int i = 0; i < 12; ++i) {
        int k = i * 256 + tid;
        float v = (k < kmax) ? W[(size_t)k * G_ + g] : 0.0f;
        wt[(size_t)n * K_TOT + k] = f2bf(v);
    }
}

// ---------------- GEMM: out[m, 0:512] = ce @ W' + bias ----------------------
// BM=128, BN=256, BK=64, 512 threads (8 waves, 2x4 of 64x64),
// grid = 128 m-panels x 2 nb = 256 blocks = 1 block/CU (m201 occupancy shape).
// A panel re-staged 2x (vs 4x at BN=128): staged bytes 1.21GB -> 804MB.
// All staging via global_load_lds (A fp32 + B bf16), source-preswizzled:
//   A rows = 256B = 16 chunks: chunk ^= (r&15)  -> 2-way (free) frag reads
//   B rows = 128B =  8 chunks: chunk ^= (v&7)   -> 2-way (free) frag reads
// 2-deep ring, counted vmcnt(8): next tile's 8 loads always in flight,
// issued one full phase (~700 cyc of 32 MFMA) ahead. No vmcnt(0) in loop.
__global__ __launch_bounds__(512, 1) void gemm_kernel(
    const float* __restrict__ events, const float* __restrict__ contexts,
    const u16* __restrict__ wt, const float* __restrict__ bias,
    float* __restrict__ out)
{
    __shared__ float Af[2][128 * 64];   // fp32 A tiles, swizzled (32 KB each)
    __shared__ u16   Bs[2][256 * 64];   // bf16 B tiles, swizzled (32 KB each)

    const int tid = threadIdx.x;
    const int bid = blockIdx.x;
    // XCD mapping: HW round-robins bid%8; both nb blocks of an A panel share
    // bid&7 -> same XCD.
    const int xx  = bid & 7;
    const int jj  = bid >> 3;            // 0..31
    const int nb  = jj & 1;
    const int mp  = (jj >> 1) * 8 + xx;  // 0..127
    const int m0  = mp * 128;

    const int lane = tid & 63;
    const int w    = tid >> 6;           // 0..7
    const int wm   = (w >> 2) * 64;
    const int wn   = (w & 3) * 64;
    const int lr   = lane & 15;
    const int kg   = lane >> 4;          // 0..3

    // ---- A staging sources: 4 chunks/thread, c = it*512+tid ->
    //      row r=c>>4, dest chunk cd=c&15, source chunk cs=cd^(r&15).
    const float* aS0[4]; const float* aS1[4]; const float* aS2[4];
    #pragma unroll
    for (int it = 0; it < 4; ++it) {
        int c  = it * 512 + tid;
        int r  = c >> 4;
        int cs = (c & 15) ^ (r & 15);
        int m = m0 + r; if (m > M_TOT - 1) m = M_TOT - 1;
        int b = m / 1023;
        int t = m - b * 1023;
        aS0[it] = events   + ((size_t)(b * L_ + t)) * H_ + cs * 4;
        aS1[it] = aS0[it] + H_;
        aS2[it] = contexts + ((size_t)(b * (L_ - 1) + t)) * H_ + cs * 4;
    }
    // ---- B staging sources: 4 chunks/thread, c = it*512+tid ->
    //      row v=c>>3 (0..255), dest chunk cd=c&7, source cs=cd^(v&7).
    const u16* bS[4];
    #pragma unroll
    for (int it = 0; it < 4; ++it) {
        int c  = it * 512 + tid;
        int v  = c >> 3;
        int cs = (c & 7) ^ (v & 7);
        bS[it] = wt + (size_t)(nb * 256 + v) * K_TOT + cs * 8;
    }

    // ---- fragment read offsets ----
    // A: float idx = row*64 + ((cw ^ (row&15))<<2), cw = ks*8 + kg*2 + {0,1}
    int aoff[4][2][2];
    // B: u16 idx = nn*64 + (((ks*4+kg) ^ (nn&7))<<3)
    int boff[4][2];
    #pragma unroll
    for (int i = 0; i < 4; ++i) {
        int row = wm + i * 16 + lr;
        int nn  = wn + i * 16 + lr;
        #pragma unroll
        for (int ks = 0; ks < 2; ++ks) {
            int cw = ks * 8 + kg * 2;
            aoff[i][ks][0] = row * 64 + ((cw       ^ (row & 15)) << 2);
            aoff[i][ks][1] = row * 64 + (((cw + 1) ^ (row & 15)) << 2);
            boff[i][ks]    = nn * 64 + (((ks * 4 + kg) ^ (nn & 7)) << 3);
        }
    }

    f32x4 acc[4][4];
    #pragma unroll
    for (int i = 0; i < 4; ++i)
        #pragma unroll
        for (int j = 0; j < 4; ++j)
            acc[i][j] = (f32x4){0.f, 0.f, 0.f, 0.f};

    auto stage = [&](int buf, int kt) {
        int k0 = kt * 64;
        int rg = kt >> 4;                // tiles never straddle source regions
        int kq = k0 & 1023;
        #pragma unroll
        for (int it = 0; it < 4; ++it) {
            const float* s = (rg == 0) ? aS0[it] : (rg == 1 ? aS1[it] : aS2[it]);
            gload16(s + kq, &Af[buf][(it * 512 + tid) * 4]);
        }
        #pragma unroll
        for (int it = 0; it < 4; ++it)
            gload16(bS[it] + k0, &Bs[buf][(it * 512 + tid) * 8]);
    };
    auto compute = [&](int buf) {
        #pragma unroll
        for (int ks = 0; ks < 2; ++ks) {
            short8 a[4], bf[4];
            #pragma unroll
            for (int i = 0; i < 4; ++i) {
                f32x4 x = *(const f32x4*)&Af[buf][aoff[i][ks][0]];
                f32x4 y = *(const f32x4*)&Af[buf][aoff[i][ks][1]];
                a[i] = cvt8(x, y);
            }
            #pragma unroll
            for (int j = 0; j < 4; ++j)
                bf[j] = *(const short8*)&Bs[buf][boff[j][ks]];
            __builtin_amdgcn_s_setprio(1);
            #pragma unroll
            for (int i = 0; i < 4; ++i)
                #pragma unroll
                for (int j = 0; j < 4; ++j)
                    acc[i][j] = __builtin_amdgcn_mfma_f32_16x16x32_bf16(
                        a[i], bf[j], acc[i][j], 0, 0, 0);
            __builtin_amdgcn_s_setprio(0);
        }
    };

#define WAITV(N)                                                               \
    asm volatile("s_waitcnt vmcnt(" #N ")" ::: "memory");                      \
    __builtin_amdgcn_sched_barrier(0);
#define LGKM0                                                                  \
    asm volatile("s_waitcnt lgkmcnt(0)" ::: "memory");                         \
    __builtin_amdgcn_sched_barrier(0);
#define BAR __builtin_amdgcn_s_barrier()

    // prologue: tile 0 in flight
    stage(0, 0);
    // main loop: tiles 0..45 (stages 1..46); tile t in buf t&1
    for (int t = 0; t < 46; t += 2) {
        stage(1, t + 1); WAITV(8); BAR; compute(0); LGKM0; BAR;
        stage(0, t + 2); WAITV(8); BAR; compute(1); LGKM0; BAR;
    }
    // tile 46 (buf0), stage 47 (buf1)
    stage(1, 47); WAITV(8); BAR; compute(0); LGKM0; BAR;
    // tile 47 (buf1)
    WAITV(0); BAR; compute(1);

#undef WAITV
#undef LGKM0
#undef BAR

    // epilogue: row = m0 + wm + i*16 + kg*4 + rr ; gcol = nb*256 + wn + j*16 + lr
    #pragma unroll
    for (int i = 0; i < 4; ++i) {
        int mloc = wm + i * 16 + kg * 4;
        #pragma unroll
        for (int j = 0; j < 4; ++j) {
            int gcol = nb * 256 + wn + j * 16 + lr;
            int seg  = gcol >> 7;
            int col  = gcol & 127;
            float bv = bias[gcol];
            float* obase = out + (size_t)seg * OUT_SEG + col;
            #pragma unroll
            for (int rr = 0; rr < 4; ++rr) {
                int mo = m0 + mloc + rr;
                if (mo < M_TOT) obase[(size_t)mo * G_] = acc[i][j][rr] + bv;
            }
        }
    }
}

// ---------------- KL reduction: stage 1 (per-block partials, no atomics) -----
__global__ __launch_bounds__(256) void kl_kernel(const float* __restrict__ out,
                                                 float* __restrict__ partial)
{
    int wid  = threadIdx.x >> 6;
    int row  = blockIdx.x * 4 + wid;        // M_TOT = 4092*4 exactly
    int lane = threadIdx.x & 63;
    const float* zm  = out;
    const float* zlv = out + OUT_SEG;
    const float* qm  = out + (size_t)2 * OUT_SEG;
    const float* qlv = out + (size_t)3 * OUT_SEG;
    size_t base = (size_t)row * G_;
    float s = 0.f;
    #pragma unroll
    for (int hh = 0; hh < 2; ++hh) {
        int g = lane + hh * 64;
        float a = zm[base + g], b = zlv[base + g];
        float c = qm[base + g], d = qlv[base + g];
        float diff = a - c;
        s += d - b + (__expf(b) + diff * diff) * __expf(-d) - 1.0f;
    }
    #pragma unroll
    for (int off = 32; off > 0; off >>= 1)
        s += __shfl_down(s, off);
    __shared__ float pw[4];
    if (lane == 0) pw[wid] = s;
    __syncthreads();
    if (threadIdx.x == 0)
        partial[blockIdx.x] = pw[0] + pw[1] + pw[2] + pw[3];
}

// ---------------- KL reduction: stage 2 --------------------------------------
__global__ __launch_bounds__(256) void kl_final(const float* __restrict__ partial,
                                                float* __restrict__ out)
{
    float s = 0.f;
    for (int i = threadIdx.x; i < KL_BLOCKS; i += 256) s += partial[i];
    #pragma unroll
    for (int off = 32; off > 0; off >>= 1)
        s += __shfl_down(s, off);
    __shared__ float pw[4];
    int wid = threadIdx.x >> 6;
    int lane = threadIdx.x & 63;
    if (lane == 0) pw[wid] = s;
    __syncthreads();
    if (threadIdx.x == 0)
        out[KL_IDX] = 0.5f * (pw[0] + pw[1] + pw[2] + pw[3]) / (float)M_TOT;
}

// ---------------- launcher ----------------------------------------------------
extern "C" void kernel_launch(void* const* d_in, const int* in_sizes, int n_in,
                              void* d_out, int out_size, void* d_ws, size_t ws_size,
                              hipStream_t stream)
{
    const float* events   = (const float*)d_in[0];
    const float* contexts = (const float*)d_in[1];
    const float* Wzm = (const float*)d_in[2];
    const float* bzm = (const float*)d_in[3];
    const float* Wzv = (const float*)d_in[4];
    const float* bzv = (const float*)d_in[5];
    const float* Wqm = (const float*)d_in[6];
    const float* bqm = (const float*)d_in[7];
    const float* Wqv = (const float*)d_in[8];
    const float* bqv = (const float*)d_in[9];
    float* out = (float*)d_out;

    u16*   wt      = (u16*)((char*)d_ws + WS_WT_OFF);
    float* bias    = (float*)((char*)d_ws + WS_BIAS_OFF);
    float* partial = (float*)((char*)d_ws + WS_PART_OFF);

    prep_kernel<<<512, 256, 0, stream>>>(Wzm, bzm, Wzv, bzv, Wqm, bqm, Wqv, bqv,
                                         wt, bias);
    gemm_kernel<<<256, 512, 0, stream>>>(events, contexts, wt, bias, out);
    kl_kernel<<<KL_BLOCKS, 256, 0, stream>>>(out, partial);
    kl_final<<<1, 256, 0, stream>>>(partial, out);
}

// Round 16
// 100.608 us; speedup vs baseline: 1.5466x; 1.0216x over previous
//
#include <hip/hip_runtime.h>
#include <stdint.h>

typedef unsigned short u16;
typedef __attribute__((ext_vector_type(8))) short short8;
typedef __attribute__((ext_vector_type(4))) float f32x4;
typedef __attribute__((ext_vector_type(2))) uint32_t u32x2;

#define B_      16
#define L_      1024
#define H_      1024
#define G_      128
#define M_TOT   16368            // B*(L-1)
#define K_TOT   3072
#define OUT_SEG 2095104          // M_TOT*G_
#define KL_IDX  (4*OUT_SEG)
#define KL_BLOCKS 4092           // M_TOT / 4 exactly

// ws layout
#define WS_WT_OFF    0           // bf16 W'T [512][3072] = 3,145,728 B
#define WS_BIAS_OFF  3145728     // float[512]
#define WS_PART_OFF  3147776     // float[4092] block partials

__device__ inline u16 f2bf(float f) {
    union { float f; uint32_t u; } x; x.f = f;
    uint32_t u = x.u;
    return (u16)((u + 0x7fffu + ((u >> 16) & 1u)) >> 16);
}

__device__ inline void gload16(const void* g, void* l) {
    __builtin_amdgcn_global_load_lds(
        (const __attribute__((address_space(1))) void*)g,
        (__attribute__((address_space(3))) void*)l, 16, 0, 0);
}

// ---------------- prep: build W'T (bf16, [512][3072]) + bias[512] ------------
__global__ __launch_bounds__(256) void prep_kernel(
    const float* __restrict__ Wzm, const float* __restrict__ bzm,
    const float* __restrict__ Wzv, const float* __restrict__ bzv,
    const float* __restrict__ Wqm, const float* __restrict__ bqm,
    const float* __restrict__ Wqv, const float* __restrict__ bqv,
    u16* __restrict__ wt, float* __restrict__ bias)
{
    int n = blockIdx.x;                 // 0..511 (output column)
    int tid = threadIdx.x;
    const float* W; const float* bsrc; int g; int kmax;
    if (n < 128)      { W = Wzm; bsrc = bzm; g = n;       kmax = 2048; }
    else if (n < 256) { W = Wzv; bsrc = bzv; g = n - 128; kmax = 2048; }
    else if (n < 384) { W = Wqm; bsrc = bqm; g = n - 256; kmax = 3072; }
    else              { W = Wqv; bsrc = bqv; g = n - 384; kmax = 3072; }
    if (tid == 0) bias[n] = bsrc[g];
    #pragma unroll
    for (int i = 0; i < 12; ++i) {
        int k = i * 256 + tid;
        float v = (k < kmax) ? W[(size_t)k * G_ + g] : 0.0f;
        wt[(size_t)n * K_TOT + k] = f2bf(v);
    }
}

// ---------------- GEMM: out[m, 0:512] = ce @ W' + bias ----------------------
// BM=128, BN=256, BK=64, 512 threads (8 waves 2x4 of 64x64), 256 blocks
// = 1 block/CU (R15 geometry). CHANGE vs R15: A is bf16 in LDS.
//   A: global f32x4 (coalesced 64B/row segments) -> named P/Q reg sets
//      (2-phase-deep pipeline) -> cvt_pk bf16 -> swizzled ds_write_b64.
//   B: global_load_lds source-preswizzled (unchanged).
// LDS = 2*(16KB A + 32KB B) = 96KB. Counted vmcnt(8): per phase 4 A-reg
// loads + 4 B-glds issued; WAITV(8) drains exactly B(t) + Aregs(t+1).
// Swizzles: A/B rows = 128B = 8 chunks of 16B, chunk ^= (row&7).
__global__ __launch_bounds__(512, 1) void gemm_kernel(
    const float* __restrict__ events, const float* __restrict__ contexts,
    const u16* __restrict__ wt, const float* __restrict__ bias,
    float* __restrict__ out)
{
    __shared__ u16 Ab[2][128 * 64];   // bf16 A tiles, swizzled (16 KB each)
    __shared__ u16 Bs[2][256 * 64];   // bf16 B tiles, swizzled (32 KB each)

    const int tid = threadIdx.x;
    const int bid = blockIdx.x;
    // Both nb blocks of an A panel share bid&7 -> same XCD.
    const int xx  = bid & 7;
    const int jj  = bid >> 3;            // 0..31
    const int nb  = jj & 1;
    const int mp  = (jj >> 1) * 8 + xx;  // 0..127
    const int m0  = mp * 128;

    const int lane = tid & 63;
    const int w    = tid >> 6;           // 0..7
    const int wm   = (w >> 2) * 64;
    const int wn   = (w & 3) * 64;
    const int lr   = lane & 15;
    const int kg   = lane >> 4;          // 0..3

    // ---- A staging: row r = tid>>2, quarter q = tid&3 (16 floats/tile) ----
    // Load j reads f32x4 at col j*16 + q*4: lanes of a row cover 64B
    // contiguous per instruction (fully coalesced).
    const int r = tid >> 2;
    const int q = tid & 3;
    int m = m0 + r; if (m > M_TOT - 1) m = M_TOT - 1;
    int bb = m / 1023;
    int tt = m - bb * 1023;
    const float* pa0 = events   + ((size_t)(bb * L_ + tt)) * H_;
    const float* pa2 = contexts + ((size_t)(bb * (L_ - 1) + tt)) * H_;
    // swizzled LDS u16 write offsets (8B ds_write_b64 each), load j ->
    // chunk cd = 2j + (q>>1), in-chunk u16 offset (q&1)*4
    int aw[4];
    #pragma unroll
    for (int j = 0; j < 4; ++j)
        aw[j] = r * 64 + (((2 * j + (q >> 1)) ^ (r & 7)) << 3) + (q & 1) * 4;

    // ---- B staging sources: 4 chunks/thread, c = it*512+tid ->
    //      row v=c>>3 (0..255), dest chunk cd=c&7, source cs=cd^(v&7).
    const u16* bS[4];
    #pragma unroll
    for (int it = 0; it < 4; ++it) {
        int c  = it * 512 + tid;
        int v  = c >> 3;
        int cs = (c & 7) ^ (v & 7);
        bS[it] = wt + (size_t)(nb * 256 + v) * K_TOT + cs * 8;
    }

    // ---- fragment read offsets (u16, swizzled; chunk cw = ks*4+kg) ----
    int aoff[4][2], boff[4][2];
    #pragma unroll
    for (int i = 0; i < 4; ++i) {
        int row = wm + i * 16 + lr;
        int nn  = wn + i * 16 + lr;
        #pragma unroll
        for (int ks = 0; ks < 2; ++ks) {
            aoff[i][ks] = row * 64 + (((ks * 4 + kg) ^ (row & 7)) << 3);
            boff[i][ks] = nn  * 64 + (((ks * 4 + kg) ^ (nn  & 7)) << 3);
        }
    }

    f32x4 acc[4][4];
    #pragma unroll
    for (int i = 0; i < 4; ++i)
        #pragma unroll
        for (int j = 0; j < 4; ++j)
            acc[i][j] = (f32x4){0.f, 0.f, 0.f, 0.f};

    auto stageB = [&](int buf, int kt) {
        int k0 = kt * 64;
        #pragma unroll
        for (int it = 0; it < 4; ++it)
            gload16(bS[it] + k0, &Bs[buf][(it * 512 + tid) * 8]);
    };
    auto compute = [&](int buf) {
        #pragma unroll
        for (int ks = 0; ks < 2; ++ks) {
            short8 a[4], bf[4];
            #pragma unroll
            for (int i = 0; i < 4; ++i)
                a[i] = *(const short8*)&Ab[buf][aoff[i][ks]];
            #pragma unroll
            for (int j = 0; j < 4; ++j)
                bf[j] = *(const short8*)&Bs[buf][boff[j][ks]];
            __builtin_amdgcn_s_setprio(1);
            #pragma unroll
            for (int i = 0; i < 4; ++i)
                #pragma unroll
                for (int j = 0; j < 4; ++j)
                    acc[i][j] = __builtin_amdgcn_mfma_f32_16x16x32_bf16(
                        a[i], bf[j], acc[i][j], 0, 0, 0);
            __builtin_amdgcn_s_setprio(0);
        }
    };

    // Named A-staging register sets (2-phase-deep; no arrays -> no scratch)
    f32x4 P0, P1, P2, P3;
    f32x4 Q0, Q1, Q2, Q3;

#define LOADA(p, KT)                                                           \
    {                                                                          \
        int k0_ = (KT) * 64;                                                   \
        int rg_ = (KT) >> 4;                                                   \
        int kq_ = (k0_ & 1023) + q * 4;                                        \
        const float* s_ = (rg_ == 0) ? pa0 : (rg_ == 1 ? (pa0 + H_) : pa2);    \
        s_ += kq_;                                                             \
        p##0 = *(const f32x4*)(s_ +  0);                                       \
        p##1 = *(const f32x4*)(s_ + 16);                                       \
        p##2 = *(const f32x4*)(s_ + 32);                                       \
        p##3 = *(const f32x4*)(s_ + 48);                                       \
    }
#define CVT1(p, J, BUF)                                                        \
    {                                                                          \
        uint32_t lo_, hi_;                                                     \
        asm("v_cvt_pk_bf16_f32 %0, %1, %2" : "=v"(lo_) : "v"(p##J[0]), "v"(p##J[1])); \
        asm("v_cvt_pk_bf16_f32 %0, %1, %2" : "=v"(hi_) : "v"(p##J[2]), "v"(p##J[3])); \
        *(u32x2*)&Ab[BUF][aw[J]] = (u32x2){lo_, hi_};                          \
    }
#define CVTW(p, BUF)  CVT1(p, 0, BUF) CVT1(p, 1, BUF) CVT1(p, 2, BUF) CVT1(p, 3, BUF)

#define WAITV(N)                                                               \
    asm volatile("s_waitcnt vmcnt(" #N ")" ::: "memory");                      \
    __builtin_amdgcn_sched_barrier(0);
#define LGKM0                                                                  \
    asm volatile("s_waitcnt lgkmcnt(0)" ::: "memory");                         \
    __builtin_amdgcn_sched_barrier(0);
#define BAR __builtin_amdgcn_s_barrier()

    // prologue: A(0) -> regs -> Ab[0]; B(0) in flight; A(1) -> Q (in flight)
    LOADA(P, 0);
    stageB(0, 0);
    WAITV(4);            // drain A(0) regs, leave B(0)
    CVTW(P, 0);
    LOADA(Q, 1);         // outstanding: B(0) 4 + Q 4 = 8
    LGKM0;               // prologue ds_writes visible before first barrier

    // even phase t: LOADA(P,t+2), consume Q=A(t+1); odd phase: swap P/Q.
    for (int t = 0; t < 46; t += 2) {
        // phase t (buf0)
        LOADA(P, t + 2);
        stageB(1, t + 1);
        WAITV(8); BAR;                 // drains B(t) + Q regs
        compute(0);
        CVTW(Q, 1);
        LGKM0; BAR;
        // phase t+1 (buf1)
        if (t + 3 < 48) LOADA(Q, t + 3);
        stageB(0, t + 2);
        WAITV(8); BAR;                 // drains B(t+1) + P regs
        compute(1);
        CVTW(P, 0);
        LGKM0; BAR;
    }
    // phase 46 (buf0): no LOADA(48); Q holds A(47)
    stageB(1, 47);
    WAITV(4); BAR;                     // drains B(46) + Q regs, leaves B(47)
    compute(0);
    CVTW(Q, 1);
    LGKM0; BAR;
    // phase 47 (buf1)
    WAITV(0); BAR;
    compute(1);

#undef LOADA
#undef CVT1
#undef CVTW
#undef WAITV
#undef LGKM0
#undef BAR

    // epilogue: row = m0 + wm + i*16 + kg*4 + rr ; gcol = nb*256 + wn + j*16 + lr
    #pragma unroll
    for (int i = 0; i < 4; ++i) {
        int mloc = wm + i * 16 + kg * 4;
        #pragma unroll
        for (int j = 0; j < 4; ++j) {
            int gcol = nb * 256 + wn + j * 16 + lr;
            int seg  = gcol >> 7;
            int col  = gcol & 127;
            float bv = bias[gcol];
            float* obase = out + (size_t)seg * OUT_SEG + col;
            #pragma unroll
            for (int rr = 0; rr < 4; ++rr) {
                int mo = m0 + mloc + rr;
                if (mo < M_TOT) obase[(size_t)mo * G_] = acc[i][j][rr] + bv;
            }
        }
    }
}

// ---------------- KL reduction: stage 1 (per-block partials, no atomics) -----
__global__ __launch_bounds__(256) void kl_kernel(const float* __restrict__ out,
                                                 float* __restrict__ partial)
{
    int wid  = threadIdx.x >> 6;
    int row  = blockIdx.x * 4 + wid;        // M_TOT = 4092*4 exactly
    int lane = threadIdx.x & 63;
    const float* zm  = out;
    const float* zlv = out + OUT_SEG;
    const float* qm  = out + (size_t)2 * OUT_SEG;
    const float* qlv = out + (size_t)3 * OUT_SEG;
    size_t base = (size_t)row * G_;
    float s = 0.f;
    #pragma unroll
    for (int hh = 0; hh < 2; ++hh) {
        int g = lane + hh * 64;
        float a = zm[base + g], b = zlv[base + g];
        float c = qm[base + g], d = qlv[base + g];
        float diff = a - c;
        s += d - b + (__expf(b) + diff * diff) * __expf(-d) - 1.0f;
    }
    #pragma unroll
    for (int off = 32; off > 0; off >>= 1)
        s += __shfl_down(s, off);
    __shared__ float pw[4];
    if (lane == 0) pw[wid] = s;
    __syncthreads();
    if (threadIdx.x == 0)
        partial[blockIdx.x] = pw[0] + pw[1] + pw[2] + pw[3];
}

// ---------------- KL reduction: stage 2 --------------------------------------
__global__ __launch_bounds__(256) void kl_final(const float* __restrict__ partial,
                                                float* __restrict__ out)
{
    float s = 0.f;
    for (int i = threadIdx.x; i < KL_BLOCKS; i += 256) s += partial[i];
    #pragma unroll
    for (int off = 32; off > 0; off >>= 1)
        s += __shfl_down(s, off);
    __shared__ float pw[4];
    int wid = threadIdx.x >> 6;
    int lane = threadIdx.x & 63;
    if (lane == 0) pw[wid] = s;
    __syncthreads();
    if (threadIdx.x == 0)
        out[KL_IDX] = 0.5f * (pw[0] + pw[1] + pw[2] + pw[3]) / (float)M_TOT;
}

// ---------------- launcher ----------------------------------------------------
extern "C" void kernel_launch(void* const* d_in, const int* in_sizes, int n_in,
                              void* d_out, int out_size, void* d_ws, size_t ws_size,
                              hipStream_t stream)
{
    const float* events   = (const float*)d_in[0];
    const float* contexts = (const float*)d_in[1];
    const float* Wzm = (const float*)d_in[2];
    const float* bzm = (const float*)d_in[3];
    const float* Wzv = (const float*)d_in[4];
    const float* bzv = (const float*)d_in[5];
    const float* Wqm = (const float*)d_in[6];
    const float* bqm = (const float*)d_in[7];
    const float* Wqv = (const float*)d_in[8];
    const float* bqv = (const float*)d_in[9];
    float* out = (float*)d_out;

    u16*   wt      = (u16*)((char*)d_ws + WS_WT_OFF);
    float* bias    = (float*)((char*)d_ws + WS_BIAS_OFF);
    float* partial = (float*)((char*)d_ws + WS_PART_OFF);

    prep_kernel<<<512, 256, 0, stream>>>(Wzm, bzm, Wzv, bzv, Wqm, bqm, Wqv, bqv,
                                         wt, bias);
    gemm_kernel<<<256, 512, 0, stream>>>(events, contexts, wt, bias, out);
    kl_kernel<<<KL_BLOCKS, 256, 0, stream>>>(out, partial);
    kl_final<<<1, 256, 0, stream>>>(partial, out);
}

// Round 17
// 96.190 us; speedup vs baseline: 1.6176x; 1.0459x over previous
//
#include <hip/hip_runtime.h>
#include <stdint.h>

typedef unsigned short u16;
typedef __attribute__((ext_vector_type(8))) short short8;
typedef __attribute__((ext_vector_type(4))) float f32x4;
typedef __attribute__((ext_vector_type(2))) uint32_t u32x2;

#define B_      16
#define L_      1024
#define H_      1024
#define G_      128
#define M_TOT   16368            // B*(L-1)
#define K_TOT   3072
#define OUT_SEG 2095104          // M_TOT*G_
#define KL_IDX  (4*OUT_SEG)
#define KL_BLOCKS 4092           // M_TOT / 4 exactly

// ws layout
#define WS_WT_OFF    0           // bf16 W'T [512][3072] = 3,145,728 B
#define WS_BIAS_OFF  3145728     // float[512]
#define WS_PART_OFF  3147776     // float[4092] block partials

__device__ inline u16 f2bf(float f) {
    union { float f; uint32_t u; } x; x.f = f;
    uint32_t u = x.u;
    return (u16)((u + 0x7fffu + ((u >> 16) & 1u)) >> 16);
}

__device__ inline void gload16(const void* g, void* l) {
    __builtin_amdgcn_global_load_lds(
        (const __attribute__((address_space(1))) void*)g,
        (__attribute__((address_space(3))) void*)l, 16, 0, 0);
}

// ---------------- prep: build W'T (bf16, [512][3072]) + bias[512] ------------
__global__ __launch_bounds__(256) void prep_kernel(
    const float* __restrict__ Wzm, const float* __restrict__ bzm,
    const float* __restrict__ Wzv, const float* __restrict__ bzv,
    const float* __restrict__ Wqm, const float* __restrict__ bqm,
    const float* __restrict__ Wqv, const float* __restrict__ bqv,
    u16* __restrict__ wt, float* __restrict__ bias)
{
    int n = blockIdx.x;                 // 0..511 (output column)
    int tid = threadIdx.x;
    const float* W; const float* bsrc; int g; int kmax;
    if (n < 128)      { W = Wzm; bsrc = bzm; g = n;       kmax = 2048; }
    else if (n < 256) { W = Wzv; bsrc = bzv; g = n - 128; kmax = 2048; }
    else if (n < 384) { W = Wqm; bsrc = bqm; g = n - 256; kmax = 3072; }
    else              { W = Wqv; bsrc = bqv; g = n - 384; kmax = 3072; }
    if (tid == 0) bias[n] = bsrc[g];
    #pragma unroll
    for (int i = 0; i < 12; ++i) {
        int k = i * 256 + tid;
        float v = (k < kmax) ? W[(size_t)k * G_ + g] : 0.0f;
        wt[(size_t)n * K_TOT + k] = f2bf(v);
    }
}

// ---------------- GEMM: out[m, 0:512] = ce @ W' + bias ----------------------
// BM=128, BN=128, BK=64, 256 threads (4 waves 2x2 of 64x64), grid 512
// -> 2 INDEPENDENT blocks/CU (the R16 schedule had 1 barrier group/CU; the
// second group fills sync gaps, m114-style). LDS = 2*(16KB A + 16KB B) = 64KB.
//   A: global f32x4 (16-rows x 64B coalesced) -> named P/Q reg sets
//      (2-phase-deep) -> cvt_pk bf16 -> swizzled ds_write_b64.
//   B: global_load_lds source-preswizzled.
// Counted vmcnt: 12 VMEM/phase (8 A + 4 B); WAITV(12) drains B(t)+Aregs(t+1).
// Swizzles: A/B rows = 128B = 8 chunks of 16B, chunk ^= (row&7).
__global__ __launch_bounds__(256, 2) void gemm_kernel(
    const float* __restrict__ events, const float* __restrict__ contexts,
    const u16* __restrict__ wt, const float* __restrict__ bias,
    float* __restrict__ out)
{
    __shared__ u16 Ab[2][128 * 64];   // bf16 A tiles, swizzled (16 KB each)
    __shared__ u16 Bs[2][128 * 64];   // bf16 B tiles, swizzled (16 KB each)

    const int tid = threadIdx.x;
    const int bid = blockIdx.x;
    // 4 nb-blocks of an A panel share bid&7 -> same XCD.
    const int xx  = bid & 7;
    const int jj  = bid >> 3;            // 0..63
    const int nb  = jj & 3;
    const int mp  = (jj >> 2) * 8 + xx;  // 0..127
    const int m0  = mp * 128;

    const int lane = tid & 63;
    const int w    = tid >> 6;           // 0..3
    const int wm   = (w >> 1) * 64;
    const int wn   = (w & 1) * 64;
    const int lr   = lane & 15;
    const int kg   = lane >> 4;          // 0..3

    // ---- A staging: rows r0=tid>>2 and r0+64; q=tid&3; 8 f32x4 loads.
    // Per instr: 16 lanes x 4 rows... lanes 4k..4k+3 cover 64B of row k.
    const int r0 = tid >> 2;
    const int q  = tid & 3;
    const float* paE[2]; const float* paC[2];
    int aw[2][4];
    #pragma unroll
    for (int g = 0; g < 2; ++g) {
        int r = r0 + g * 64;
        int m = m0 + r; if (m > M_TOT - 1) m = M_TOT - 1;
        int b = m / 1023;
        int t = m - b * 1023;
        paE[g] = events   + ((size_t)(b * L_ + t)) * H_;
        paC[g] = contexts + ((size_t)(b * (L_ - 1) + t)) * H_;
        #pragma unroll
        for (int j = 0; j < 4; ++j)
            aw[g][j] = r * 64 + (((2 * j + (q >> 1)) ^ (r & 7)) << 3)
                     + (q & 1) * 4;
    }

    // ---- B staging: 4 gload_lds chunks/thread, source-preswizzled ----
    const u16* bS[4];
    #pragma unroll
    for (int it = 0; it < 4; ++it) {
        int c  = it * 256 + tid;
        int v  = c >> 3;
        int cs = (c & 7) ^ (v & 7);
        bS[it] = wt + (size_t)(nb * 128 + v) * K_TOT + cs * 8;
    }

    // ---- fragment read offsets (u16, swizzled; chunk cw = ks*4+kg) ----
    int aoff[4][2], boff[4][2];
    #pragma unroll
    for (int i = 0; i < 4; ++i) {
        int row = wm + i * 16 + lr;
        int nn  = wn + i * 16 + lr;
        #pragma unroll
        for (int ks = 0; ks < 2; ++ks) {
            aoff[i][ks] = row * 64 + (((ks * 4 + kg) ^ (row & 7)) << 3);
            boff[i][ks] = nn  * 64 + (((ks * 4 + kg) ^ (nn  & 7)) << 3);
        }
    }

    f32x4 acc[4][4];
    #pragma unroll
    for (int i = 0; i < 4; ++i)
        #pragma unroll
        for (int j = 0; j < 4; ++j)
            acc[i][j] = (f32x4){0.f, 0.f, 0.f, 0.f};

    auto stageB = [&](int buf, int kt) {
        int k0 = kt * 64;
        #pragma unroll
        for (int it = 0; it < 4; ++it)
            gload16(bS[it] + k0, &Bs[buf][(it * 256 + tid) * 8]);
    };
    auto compute = [&](int buf) {
        #pragma unroll
        for (int ks = 0; ks < 2; ++ks) {
            short8 a[4], bf[4];
            #pragma unroll
            for (int i = 0; i < 4; ++i)
                a[i] = *(const short8*)&Ab[buf][aoff[i][ks]];
            #pragma unroll
            for (int j = 0; j < 4; ++j)
                bf[j] = *(const short8*)&Bs[buf][boff[j][ks]];
            __builtin_amdgcn_s_setprio(1);
            #pragma unroll
            for (int i = 0; i < 4; ++i)
                #pragma unroll
                for (int j = 0; j < 4; ++j)
                    acc[i][j] = __builtin_amdgcn_mfma_f32_16x16x32_bf16(
                        a[i], bf[j], acc[i][j], 0, 0, 0);
            __builtin_amdgcn_s_setprio(0);
        }
    };

    // Named A-staging register sets (2-phase-deep; no arrays -> no scratch)
    f32x4 P0, P1, P2, P3, P4, P5, P6, P7;
    f32x4 Q0, Q1, Q2, Q3, Q4, Q5, Q6, Q7;

#define LOADA(p, KT)                                                           \
    {                                                                          \
        int k0_ = (KT) * 64;                                                   \
        int rg_ = (KT) >> 4;                                                   \
        int kq_ = (k0_ & 1023) + q * 4;                                        \
        const float* s0_ = (rg_ == 0) ? paE[0]                                 \
                          : (rg_ == 1 ? (paE[0] + H_) : paC[0]);               \
        const float* s1_ = (rg_ == 0) ? paE[1]                                 \
                          : (rg_ == 1 ? (paE[1] + H_) : paC[1]);               \
        s0_ += kq_; s1_ += kq_;                                                \
        p##0 = *(const f32x4*)(s0_ +  0);                                      \
        p##1 = *(const f32x4*)(s0_ + 16);                                      \
        p##2 = *(const f32x4*)(s0_ + 32);                                      \
        p##3 = *(const f32x4*)(s0_ + 48);                                      \
        p##4 = *(const f32x4*)(s1_ +  0);                                      \
        p##5 = *(const f32x4*)(s1_ + 16);                                      \
        p##6 = *(const f32x4*)(s1_ + 32);                                      \
        p##7 = *(const f32x4*)(s1_ + 48);                                      \
    }
#define CVT1(p, RI, G, J, BUF)                                                 \
    {                                                                          \
        uint32_t lo_, hi_;                                                     \
        asm("v_cvt_pk_bf16_f32 %0, %1, %2" : "=v"(lo_) : "v"(p##RI[0]), "v"(p##RI[1])); \
        asm("v_cvt_pk_bf16_f32 %0, %1, %2" : "=v"(hi_) : "v"(p##RI[2]), "v"(p##RI[3])); \
        *(u32x2*)&Ab[BUF][aw[G][J]] = (u32x2){lo_, hi_};                       \
    }
#define CVTW(p, BUF)                                                           \
    CVT1(p, 0, 0, 0, BUF) CVT1(p, 1, 0, 1, BUF)                                \
    CVT1(p, 2, 0, 2, BUF) CVT1(p, 3, 0, 3, BUF)                                \
    CVT1(p, 4, 1, 0, BUF) CVT1(p, 5, 1, 1, BUF)                                \
    CVT1(p, 6, 1, 2, BUF) CVT1(p, 7, 1, 3, BUF)

#define WAITV(N)                                                               \
    asm volatile("s_waitcnt vmcnt(" #N ")" ::: "memory");                      \
    __builtin_amdgcn_sched_barrier(0);
#define LGKM0                                                                  \
    asm volatile("s_waitcnt lgkmcnt(0)" ::: "memory");                         \
    __builtin_amdgcn_sched_barrier(0);
#define BAR __builtin_amdgcn_s_barrier()

    // prologue: A(0)->regs->Ab[0]; B(0) in flight; A(1)->Q (in flight)
    LOADA(P, 0);
    stageB(0, 0);
    WAITV(4);            // drain P = A(0) regs, leave B(0)
    CVTW(P, 0);
    LOADA(Q, 1);         // outstanding: B(0) 4 + Q 8 = 12
    LGKM0;               // prologue ds_writes done before first barrier

    for (int t = 0; t < 46; t += 2) {
        // phase t (buf0): consume Q=A(t+1) after WAITV
        LOADA(P, t + 2);
        stageB(1, t + 1);
        WAITV(12); BAR;                // drains B(t) + Q regs
        compute(0);
        CVTW(Q, 1);
        LGKM0; BAR;
        // phase t+1 (buf1)
        LOADA(Q, t + 3);
        stageB(0, t + 2);
        WAITV(12); BAR;                // drains B(t+1) + P regs
        compute(1);
        CVTW(P, 0);
        LGKM0; BAR;
    }
    // phase 46 (buf0): Q holds A(47); no more A loads
    stageB(1, 47);
    WAITV(4); BAR;                     // drains B(46) + Q regs, leaves B(47)
    compute(0);
    CVTW(Q, 1);
    LGKM0; BAR;
    // phase 47 (buf1)
    WAITV(0); BAR;
    compute(1);

#undef LOADA
#undef CVT1
#undef CVTW
#undef WAITV
#undef LGKM0
#undef BAR

    // epilogue: row = m0 + wm + i*16 + kg*4 + rr ; gcol = nb*128 + wn + j*16 + lr
    const float* bptr = bias + nb * 128;
    float* obase = out + (size_t)nb * OUT_SEG;
    #pragma unroll
    for (int i = 0; i < 4; ++i) {
        int mloc = wm + i * 16 + kg * 4;
        #pragma unroll
        for (int j = 0; j < 4; ++j) {
            int g = wn + j * 16 + lr;
            float bv = bptr[g];
            #pragma unroll
            for (int rr = 0; rr < 4; ++rr) {
                int mo = m0 + mloc + rr;
                if (mo < M_TOT) obase[(size_t)mo * G_ + g] = acc[i][j][rr] + bv;
            }
        }
    }
}

// ---------------- KL reduction: stage 1 (per-block partials, no atomics) -----
__global__ __launch_bounds__(256) void kl_kernel(const float* __restrict__ out,
                                                 float* __restrict__ partial)
{
    int wid  = threadIdx.x >> 6;
    int row  = blockIdx.x * 4 + wid;        // M_TOT = 4092*4 exactly
    int lane = threadIdx.x & 63;
    const float* zm  = out;
    const float* zlv = out + OUT_SEG;
    const float* qm  = out + (size_t)2 * OUT_SEG;
    const float* qlv = out + (size_t)3 * OUT_SEG;
    size_t base = (size_t)row * G_;
    float s = 0.f;
    #pragma unroll
    for (int hh = 0; hh < 2; ++hh) {
        int g = lane + hh * 64;
        float a = zm[base + g], b = zlv[base + g];
        float c = qm[base + g], d = qlv[base + g];
        float diff = a - c;
        s += d - b + (__expf(b) + diff * diff) * __expf(-d) - 1.0f;
    }
    #pragma unroll
    for (int off = 32; off > 0; off >>= 1)
        s += __shfl_down(s, off);
    __shared__ float pw[4];
    if (lane == 0) pw[wid] = s;
    __syncthreads();
    if (threadIdx.x == 0)
        partial[blockIdx.x] = pw[0] + pw[1] + pw[2] + pw[3];
}

// ---------------- KL reduction: stage 2 --------------------------------------
__global__ __launch_bounds__(256) void kl_final(const float* __restrict__ partial,
                                                float* __restrict__ out)
{
    float s = 0.f;
    for (int i = threadIdx.x; i < KL_BLOCKS; i += 256) s += partial[i];
    #pragma unroll
    for (int off = 32; off > 0; off >>= 1)
        s += __shfl_down(s, off);
    __shared__ float pw[4];
    int wid = threadIdx.x >> 6;
    int lane = threadIdx.x & 63;
    if (lane == 0) pw[wid] = s;
    __syncthreads();
    if (threadIdx.x == 0)
        out[KL_IDX] = 0.5f * (pw[0] + pw[1] + pw[2] + pw[3]) / (float)M_TOT;
}

// ---------------- launcher ----------------------------------------------------
extern "C" void kernel_launch(void* const* d_in, const int* in_sizes, int n_in,
                              void* d_out, int out_size, void* d_ws, size_t ws_size,
                              hipStream_t stream)
{
    const float* events   = (const float*)d_in[0];
    const float* contexts = (const float*)d_in[1];
    const float* Wzm = (const float*)d_in[2];
    const float* bzm = (const float*)d_in[3];
    const float* Wzv = (const float*)d_in[4];
    const float* bzv = (const float*)d_in[5];
    const float* Wqm = (const float*)d_in[6];
    const float* bqm = (const float*)d_in[7];
    const float* Wqv = (const float*)d_in[8];
    const float* bqv = (const float*)d_in[9];
    float* out = (float*)d_out;

    u16*   wt      = (u16*)((char*)d_ws + WS_WT_OFF);
    float* bias    = (float*)((char*)d_ws + WS_BIAS_OFF);
    float* partial = (float*)((char*)d_ws + WS_PART_OFF);

    prep_kernel<<<512, 256, 0, stream>>>(Wzm, bzm, Wzv, bzv, Wqm, bqm, Wqv, bqv,
                                         wt, bias);
    gemm_kernel<<<512, 256, 0, stream>>>(events, contexts, wt, bias, out);
    kl_kernel<<<KL_BLOCKS, 256, 0, stream>>>(out, partial);
    kl_final<<<1, 256, 0, stream>>>(partial, out);
}